// Round 8
// baseline (625.315 us; speedup 1.0000x reference)
//
#include <hip/hip_runtime.h>
#include <hip/hip_bf16.h>
#include <math.h>

// Problem constants: B=2,S=1024 -> T=2048; E=8,K=2,H=768,F=3072 (fp32 in/out)
#define T_TOK 2048
#define EXP   8
#define HID   768
#define FFN   3072
#define MAXTILES 40     // 128-row tiles: sum_e ceil(cnt_e/128) <= 39

typedef __bf16 bf16x8 __attribute__((ext_vector_type(8)));
typedef float  f32x4  __attribute__((ext_vector_type(4)));
typedef short  s16x8  __attribute__((ext_vector_type(8)));

// ---------------- workspace layout (bytes) ----------------
// Pack format ("staging-linear"): per (tile, ktile) a 16 KB block of
// 16 slabs x 1KB; slab = p*8 + kg*2 + half; within slab: [row64][8 shorts].
// A staging instruction reads slab_base + lane*16 -> fully contiguous 1 KB.
#define WS_CNT      0
#define WS_OFFS     64
#define WS_NTILES   128
#define WS_TILEE    256
#define WS_TILEROW  1280
#define WS_TKE      4096
#define WS_TKP      20480
#define WS_TOKIDS   36864
#define WS_PW       53248
#define WS_XPK      131072                       // 40*24*16KB   = 15,728,640
#define WS_W1PK     (WS_XPK  + 15728640)         // 8*24*24*16KB = 75,497,472
#define WS_W2PK     (WS_W1PK + 75497472)         // 8*6*96*16KB  = 75,497,472
#define WS_HMA      (WS_W2PK + 75497472)         // 40*96*16KB   = 62,914,560
// end = 229,769,216 (~219 MiB)

// ---------------- helpers ----------------
__device__ __forceinline__ void gload16(const void* g, void* l) {
    __builtin_amdgcn_global_load_lds((__attribute__((address_space(1))) void*)g,
                                     (__attribute__((address_space(3))) void*)l,
                                     16, 0, 0);
}

__device__ __forceinline__ void split_bf16(float f, short& hi, short& lo) {
    unsigned u  = __float_as_uint(f);
    unsigned h  = (u + 0x8000u) >> 16;            // RN to bf16
    float    hf = __uint_as_float(h << 16);
    float    lf = f - hf;                          // exact in fp32
    unsigned l  = (__float_as_uint(lf) + 0x8000u) >> 16;
    hi = (short)h; lo = (short)l;
}

__device__ __forceinline__ float gelu_exact(float v) {
    return 0.5f * v * (1.0f + erff(v * 0.70710678118654752f));
}

// ---------------- init ----------------
__global__ void k_init(float* __restrict__ out, int* __restrict__ cnt) {
    int idx = blockIdx.x * blockDim.x + threadIdx.x;
    const int n = T_TOK * HID;
    for (int i = idx; i < n; i += gridDim.x * blockDim.x) out[i] = 0.f;
    if (idx < EXP) cnt[idx] = 0;
}

// ---------------- router: one wave per token ----------------
__global__ __launch_bounds__(256) void k_router(
    const float* __restrict__ x, const float* __restrict__ rw,
    int* __restrict__ tk_e, float* __restrict__ tk_p, int* __restrict__ cnt)
{
    int wave = threadIdx.x >> 6;
    int lane = threadIdx.x & 63;
    int t = blockIdx.x * 4 + wave;
    if (t >= T_TOK) return;

    float acc[EXP];
#pragma unroll
    for (int e = 0; e < EXP; ++e) acc[e] = 0.f;
    const float* xr = x + (size_t)t * HID;
#pragma unroll
    for (int i = 0; i < HID / 64; ++i) {
        int k = i * 64 + lane;
        float xv = xr[k];
#pragma unroll
        for (int e = 0; e < EXP; ++e) acc[e] += xv * rw[e * HID + k];
    }
#pragma unroll
    for (int e = 0; e < EXP; ++e) {
        float v = acc[e];
#pragma unroll
        for (int off = 32; off > 0; off >>= 1) v += __shfl_xor(v, off);
        acc[e] = v;
    }
    int e0 = 0; float v0 = acc[0];
#pragma unroll
    for (int e = 1; e < EXP; ++e) if (acc[e] > v0) { v0 = acc[e]; e0 = e; }
    int e1 = -1; float v1 = -INFINITY;
#pragma unroll
    for (int e = 0; e < EXP; ++e) if (e != e0 && acc[e] > v1) { v1 = acc[e]; e1 = e; }
    float ex = expf(v1 - v0);
    float p0 = 1.f / (1.f + ex);
    float p1 = ex / (1.f + ex);

    if (lane == 0) {
        tk_e[t * 2 + 0] = e0; tk_e[t * 2 + 1] = e1;
        tk_p[t * 2 + 0] = p0; tk_p[t * 2 + 1] = p1;
        atomicAdd(&cnt[e0], 1);
        atomicAdd(&cnt[e1], 1);
    }
}

// ---------------- scatter (128-row tiles) ----------------
__global__ __launch_bounds__(256) void k_scatter(
    const int* __restrict__ cnt, int* __restrict__ offs, int* __restrict__ nTiles,
    int* __restrict__ tileE, int* __restrict__ tileRow,
    const int* __restrict__ tk_e, const float* __restrict__ tk_p,
    int* __restrict__ token_ids, float* __restrict__ pw)
{
    __shared__ int fill[EXP];
    __shared__ int offsS[EXP + 1];
    if (threadIdx.x == 0) {
        int o = 0;
        for (int e = 0; e < EXP; ++e) { offsS[e] = o; offs[e] = o; o += cnt[e]; }
        offsS[EXP] = o; offs[EXP] = o;
        int nt = 0;
        for (int e = 0; e < EXP; ++e)
            for (int r = 0; r < cnt[e]; r += 128) {
                tileE[nt] = e; tileRow[nt] = offsS[e] + r; ++nt;
            }
        *nTiles = nt;
    }
    if (threadIdx.x < EXP) fill[threadIdx.x] = 0;
    __syncthreads();
    for (int t = threadIdx.x; t < T_TOK; t += 256) {
#pragma unroll
        for (int kk = 0; kk < 2; ++kk) {
            int e = tk_e[t * 2 + kk];
            int slot = atomicAdd(&fill[e], 1);
            int g = offsS[e] + slot;
            token_ids[g] = t;
            pw[g] = tk_p[t * 2 + kk];
        }
    }
}

// ---------------- weight pack: fp32 [E][N][K] -> staging-linear hi/lo ----
__global__ __launch_bounds__(256) void k_packw(
    const float* __restrict__ W, short* __restrict__ pk, int N, int K)
{
    int unit = blockIdx.x * 4 + (threadIdx.x >> 6);
    int lane = threadIdx.x & 63;
    int NTN = N >> 7, NTK = K >> 5;
    int half = unit & 1;
    int u2   = unit >> 1;
    int kt   = u2 % NTK;
    int ent  = u2 / NTK;                 // e*NTN + nt
    int nt   = ent % NTN;
    int e    = ent / NTN;
    int row  = nt * 128 + half * 64 + lane;

    const float* src = W + ((size_t)e * N + row) * K + kt * 32;
    s16x8 h4[4], l4v[4];
#pragma unroll
    for (int c = 0; c < 32; c += 4) {
        float4 f = *(const float4*)(src + c);
        short hh, ll;
        split_bf16(f.x, hh, ll); h4[c >> 3][(c & 7) + 0] = hh; l4v[c >> 3][(c & 7) + 0] = ll;
        split_bf16(f.y, hh, ll); h4[c >> 3][(c & 7) + 1] = hh; l4v[c >> 3][(c & 7) + 1] = ll;
        split_bf16(f.z, hh, ll); h4[c >> 3][(c & 7) + 2] = hh; l4v[c >> 3][(c & 7) + 2] = ll;
        split_bf16(f.w, hh, ll); h4[c >> 3][(c & 7) + 3] = hh; l4v[c >> 3][(c & 7) + 3] = ll;
    }
    short* base = pk + ((size_t)ent * NTK + kt) * 8192;
#pragma unroll
    for (int kg = 0; kg < 4; ++kg) {
        *(s16x8*)(base + (0 * 8 + kg * 2 + half) * 512 + lane * 8) = h4[kg];
        *(s16x8*)(base + (1 * 8 + kg * 2 + half) * 512 + lane * 8) = l4v[kg];
    }
}

// ---------------- x pack: gathered token rows -> staging-linear ----------
__global__ __launch_bounds__(256) void k_packx(
    const float* __restrict__ x, const int* __restrict__ token_ids,
    const int* __restrict__ tileE, const int* __restrict__ tileRow,
    const int* __restrict__ offs, const int* __restrict__ nTiles,
    short* __restrict__ xpk)
{
    int unit = blockIdx.x * 4 + (threadIdx.x >> 6);
    int lane = threadIdx.x & 63;
    int half = unit & 1;
    int u2   = unit >> 1;
    int kt   = u2 % 24;
    int tile = u2 / 24;
    if (tile >= *nTiles) return;
    int e = tileE[tile];
    int rowEnd = offs[e + 1];
    int g = min(tileRow[tile] + half * 64 + lane, rowEnd - 1);
    int t = token_ids[g];

    const float* src = x + (size_t)t * HID + kt * 32;
    s16x8 h4[4], l4v[4];
#pragma unroll
    for (int c = 0; c < 32; c += 4) {
        float4 f = *(const float4*)(src + c);
        short hh, ll;
        split_bf16(f.x, hh, ll); h4[c >> 3][(c & 7) + 0] = hh; l4v[c >> 3][(c & 7) + 0] = ll;
        split_bf16(f.y, hh, ll); h4[c >> 3][(c & 7) + 1] = hh; l4v[c >> 3][(c & 7) + 1] = ll;
        split_bf16(f.z, hh, ll); h4[c >> 3][(c & 7) + 2] = hh; l4v[c >> 3][(c & 7) + 2] = ll;
        split_bf16(f.w, hh, ll); h4[c >> 3][(c & 7) + 3] = hh; l4v[c >> 3][(c & 7) + 3] = ll;
    }
    short* base = xpk + ((size_t)tile * 24 + kt) * 8192;
#pragma unroll
    for (int kg = 0; kg < 4; ++kg) {
        *(s16x8*)(base + (0 * 8 + kg * 2 + half) * 512 + lane * 8) = h4[kg];
        *(s16x8*)(base + (1 * 8 + kg * 2 + half) * 512 + lane * 8) = l4v[kg];
    }
}

// ================= MFMA GEMMs: bf16x3 split, 128x128 tile =================
// TK=32. 4 waves 2x2, wave tile 64x64 = 4x4 frags of 16x16, 48 MFMA/wave/iter.
// All staging loads contiguous 1KB. T3/T4: TRIPLE-buffered LDS (96KB,
// 1 block/CU), depth-2 prefetch with counted s_waitcnt vmcnt(8) + raw
// s_barrier -- loads for step kt issued at kt-2 stay in flight ~2 K-steps,
// covering HBM latency; vmcnt never drains to 0 in the main loop (except
// the final step, where only its own batch is outstanding).
// Hazards: RAW = per-wave vmcnt(8) then barrier => all slabs for kt landed.
// WAR = issue into buf[(kt+2)%3] happens after the kt barrier, by which
// every wave consumed that buffer at kt-1. No other vmem ops in the loop.

#define DBUF 16384   // shorts per buffer (32 KB); 3 buffers

__global__ __launch_bounds__(256) void k_gemm1_mfma(
    const short* __restrict__ xpk, const short* __restrict__ w1pk,
    const float* __restrict__ b1, short* __restrict__ hmA,
    const int* __restrict__ tileE, const int* __restrict__ tileRow,
    const int* __restrict__ offs, const int* __restrict__ nTiles)
{
    const int lin = blockIdx.x;                 // 0..959
    const int swz = (lin & 7) * 120 + (lin >> 3);
    const int bx   = swz % 24;                  // N-block (24 x 128 = 3072)
    const int tile = swz / 24;
    if (tile >= *nTiles) return;
    const int e = tileE[tile];
    const int rowBase = tileRow[tile];
    const int rowEnd = offs[e + 1];
    const int n0 = bx * 128;

    __shared__ __align__(16) short S[3][DBUF];   // 96 KB

    const int tid = threadIdx.x;
    const int lane = tid & 63;
    const int w = tid >> 6;
    const int wm = w & 1, wn = w >> 1;
    const int l15 = lane & 15, l4 = lane >> 4;

    // 32 slabs (1KB) per K-step, 8 per wave; s: ab=s>>4, p=(s>>3)&1,
    // kg=(s>>1)&3, h=s&1. jdst = ((ab*2+p)*4+kg)*1024 + h*512 shorts.
    const short* jsrc[8];
    int jdst[8];
#pragma unroll
    for (int j = 0; j < 8; ++j) {
        int s = w + j * 4;
        int ab = s >> 4, p = (s >> 3) & 1, kg = (s >> 1) & 3, h = s & 1;
        jdst[j] = ((ab * 2 + p) * 4 + kg) * 1024 + h * 512;
        if (ab == 0)
            jsrc[j] = xpk + (size_t)tile * 24 * 8192 + s * 512 + lane * 8;
        else
            jsrc[j] = w1pk + ((size_t)(e * 24 + bx) * 24) * 8192
                      + (s - 16) * 512 + lane * 8;
    }

    f32x4 acc[4][4] = {};

    const int NT = 24;
    // prologue: fill buffers 0 and 1 (depth-2)
#pragma unroll
    for (int j = 0; j < 8; ++j) gload16(jsrc[j], (void*)&S[0][jdst[j]]);
#pragma unroll
    for (int j = 0; j < 8; ++j) gload16(jsrc[j] + 8192, (void*)&S[1][jdst[j]]);

    int cur = 0;
    for (int kt = 0; kt < NT; ++kt) {
        if (kt + 1 < NT) asm volatile("s_waitcnt vmcnt(8)" ::: "memory");
        else             asm volatile("s_waitcnt vmcnt(0)" ::: "memory");
        __builtin_amdgcn_s_barrier();
        if (kt + 2 < NT) {                       // issue depth-2 prefetch
            int nb = cur + 2; if (nb >= 3) nb -= 3;
            size_t k0 = (size_t)(kt + 2) * 8192;
#pragma unroll
            for (int j = 0; j < 8; ++j) gload16(jsrc[j] + k0, (void*)&S[nb][jdst[j]]);
        }
        const short* base = S[cur];
        bf16x8 ah[4], al[4], bh[4], bl[4];
#pragma unroll
        for (int mf = 0; mf < 4; ++mf) {
            int r = wm * 64 + mf * 16 + l15;
            ah[mf] = *(const bf16x8*)(base + (0 * 4 + l4) * 1024 + r * 8);
            al[mf] = *(const bf16x8*)(base + (1 * 4 + l4) * 1024 + r * 8);
        }
#pragma unroll
        for (int nf = 0; nf < 4; ++nf) {
            int c = wn * 64 + nf * 16 + l15;
            bh[nf] = *(const bf16x8*)(base + (2 * 4 + l4) * 1024 + c * 8);
            bl[nf] = *(const bf16x8*)(base + (3 * 4 + l4) * 1024 + c * 8);
        }
#pragma unroll
        for (int mf = 0; mf < 4; ++mf)
#pragma unroll
            for (int nf = 0; nf < 4; ++nf)
                acc[mf][nf] = __builtin_amdgcn_mfma_f32_16x16x32_bf16(ah[mf], bh[nf], acc[mf][nf], 0, 0, 0);
#pragma unroll
        for (int mf = 0; mf < 4; ++mf)
#pragma unroll
            for (int nf = 0; nf < 4; ++nf)
                acc[mf][nf] = __builtin_amdgcn_mfma_f32_16x16x32_bf16(ah[mf], bl[nf], acc[mf][nf], 0, 0, 0);
#pragma unroll
        for (int mf = 0; mf < 4; ++mf)
#pragma unroll
            for (int nf = 0; nf < 4; ++nf)
                acc[mf][nf] = __builtin_amdgcn_mfma_f32_16x16x32_bf16(al[mf], bh[nf], acc[mf][nf], 0, 0, 0);
        ++cur; if (cur >= 3) cur -= 3;
    }

    // epilogue: bias + exact GELU + split-store DIRECTLY in gemm2's A-pack
    // C/D map: col = lane&15, row = (lane>>4)*4 + reg   (m89/m91)
#pragma unroll
    for (int mf = 0; mf < 4; ++mf)
#pragma unroll
        for (int nf = 0; nf < 4; ++nf) {
            int f = n0 + wn * 64 + nf * 16 + l15;
            float bias = b1[e * FFN + f];
            int ktf = f >> 5, kg = (f >> 3) & 3, sh = f & 7;
            size_t kbase = ((size_t)tile * 96 + ktf) * 8192 + (kg * 2) * 512 + sh;
#pragma unroll
            for (int j = 0; j < 4; ++j) {
                int row = wm * 64 + mf * 16 + l4 * 4 + j;
                if (rowBase + row < rowEnd) {
                    float v = gelu_exact(acc[mf][nf][j] + bias);
                    short hi, lo;
                    split_bf16(v, hi, lo);
                    size_t o = kbase + (row >> 6) * 512 + (row & 63) * 8;
                    hmA[o] = hi;            // plane 0
                    hmA[o + 4096] = lo;     // plane 1 (slab +8)
                }
            }
        }
}

__global__ __launch_bounds__(256) void k_gemm2_mfma(
    const short* __restrict__ hmA, const short* __restrict__ w2pk,
    const float* __restrict__ b2, float* __restrict__ out,
    const int* __restrict__ token_ids, const float* __restrict__ pw,
    const int* __restrict__ tileE, const int* __restrict__ tileRow,
    const int* __restrict__ offs, const int* __restrict__ nTiles)
{
    const int lin = blockIdx.x;                 // 0..959
    const int swz = (lin & 7) * 120 + (lin >> 3);
    const int sub = swz % 24;                   // (x,z) innermost per tile
    const int bx  = sub % 6;                    // N-block (6 x 128 = 768)
    const int z   = sub / 6;                    // split-K = 4
    const int tile = swz / 24;
    if (tile >= *nTiles) return;
    const int e = tileE[tile];
    const int rowBase = tileRow[tile];
    const int rowEnd = offs[e + 1];
    const int n0 = bx * 128;

    __shared__ __align__(16) short S[3][DBUF];   // 96 KB

    const int tid = threadIdx.x;
    const int lane = tid & 63;
    const int w = tid >> 6;
    const int wm = w & 1, wn = w >> 1;
    const int l15 = lane & 15, l4 = lane >> 4;

    const short* jsrc[8];
    int jdst[8];
#pragma unroll
    for (int j = 0; j < 8; ++j) {
        int s = w + j * 4;
        int ab = s >> 4, p = (s >> 3) & 1, kg = (s >> 1) & 3, h = s & 1;
        jdst[j] = ((ab * 2 + p) * 4 + kg) * 1024 + h * 512;
        if (ab == 0)
            jsrc[j] = hmA + ((size_t)tile * 96 + z * 24) * 8192 + s * 512 + lane * 8;
        else
            jsrc[j] = w2pk + ((size_t)(e * 6 + bx) * 96 + z * 24) * 8192
                      + (s - 16) * 512 + lane * 8;
    }

    f32x4 acc[4][4] = {};

    const int NT = 24;
#pragma unroll
    for (int j = 0; j < 8; ++j) gload16(jsrc[j], (void*)&S[0][jdst[j]]);
#pragma unroll
    for (int j = 0; j < 8; ++j) gload16(jsrc[j] + 8192, (void*)&S[1][jdst[j]]);

    int cur = 0;
    for (int kt = 0; kt < NT; ++kt) {
        if (kt + 1 < NT) asm volatile("s_waitcnt vmcnt(8)" ::: "memory");
        else             asm volatile("s_waitcnt vmcnt(0)" ::: "memory");
        __builtin_amdgcn_s_barrier();
        if (kt + 2 < NT) {
            int nb = cur + 2; if (nb >= 3) nb -= 3;
            size_t k0 = (size_t)(kt + 2) * 8192;
#pragma unroll
            for (int j = 0; j < 8; ++j) gload16(jsrc[j] + k0, (void*)&S[nb][jdst[j]]);
        }
        const short* base = S[cur];
        bf16x8 ah[4], al[4], bh[4], bl[4];
#pragma unroll
        for (int mf = 0; mf < 4; ++mf) {
            int r = wm * 64 + mf * 16 + l15;
            ah[mf] = *(const bf16x8*)(base + (0 * 4 + l4) * 1024 + r * 8);
            al[mf] = *(const bf16x8*)(base + (1 * 4 + l4) * 1024 + r * 8);
        }
#pragma unroll
        for (int nf = 0; nf < 4; ++nf) {
            int c = wn * 64 + nf * 16 + l15;
            bh[nf] = *(const bf16x8*)(base + (2 * 4 + l4) * 1024 + c * 8);
            bl[nf] = *(const bf16x8*)(base + (3 * 4 + l4) * 1024 + c * 8);
        }
#pragma unroll
        for (int mf = 0; mf < 4; ++mf)
#pragma unroll
            for (int nf = 0; nf < 4; ++nf)
                acc[mf][nf] = __builtin_amdgcn_mfma_f32_16x16x32_bf16(ah[mf], bh[nf], acc[mf][nf], 0, 0, 0);
#pragma unroll
        for (int mf = 0; mf < 4; ++mf)
#pragma unroll
            for (int nf = 0; nf < 4; ++nf)
                acc[mf][nf] = __builtin_amdgcn_mfma_f32_16x16x32_bf16(ah[mf], bl[nf], acc[mf][nf], 0, 0, 0);
#pragma unroll
        for (int mf = 0; mf < 4; ++mf)
#pragma unroll
            for (int nf = 0; nf < 4; ++nf)
                acc[mf][nf] = __builtin_amdgcn_mfma_f32_16x16x32_bf16(al[mf], bh[nf], acc[mf][nf], 0, 0, 0);
        ++cur; if (cur >= 3) cur -= 3;
    }

    // epilogue: (acc [+ b2 if z==0]) * p, atomicAdd into out
#pragma unroll
    for (int mf = 0; mf < 4; ++mf)
#pragma unroll
        for (int nf = 0; nf < 4; ++nf) {
            int h = n0 + wn * 64 + nf * 16 + l15;
            float bias = (z == 0) ? b2[e * HID + h] : 0.f;
#pragma unroll
            for (int j = 0; j < 4; ++j) {
                int g = rowBase + wm * 64 + mf * 16 + l4 * 4 + j;
                if (g < rowEnd) {
                    int t = token_ids[g];
                    float p = pw[g];
                    atomicAdd(&out[(size_t)t * HID + h], (acc[mf][nf][j] + bias) * p);
                }
            }
        }
}

// ---------------- launch ----------------
extern "C" void kernel_launch(void* const* d_in, const int* in_sizes, int n_in,
                              void* d_out, int out_size, void* d_ws, size_t ws_size,
                              hipStream_t stream) {
    const float* x  = (const float*)d_in[0];
    const float* rw = (const float*)d_in[1];
    const float* w1 = (const float*)d_in[2];
    const float* b1 = (const float*)d_in[3];
    const float* w2 = (const float*)d_in[4];
    const float* b2 = (const float*)d_in[5];
    float* out = (float*)d_out;

    char* ws = (char*)d_ws;
    int*   cnt       = (int*)(ws + WS_CNT);
    int*   offs      = (int*)(ws + WS_OFFS);
    int*   nTiles    = (int*)(ws + WS_NTILES);
    int*   tileE     = (int*)(ws + WS_TILEE);
    int*   tileRow   = (int*)(ws + WS_TILEROW);
    int*   tk_e      = (int*)(ws + WS_TKE);
    float* tk_p      = (float*)(ws + WS_TKP);
    int*   token_ids = (int*)(ws + WS_TOKIDS);
    float* pw        = (float*)(ws + WS_PW);
    short* xpk  = (short*)(ws + WS_XPK);
    short* w1pk = (short*)(ws + WS_W1PK);
    short* w2pk = (short*)(ws + WS_W2PK);
    short* hmA  = (short*)(ws + WS_HMA);

    k_init<<<1024, 256, 0, stream>>>(out, cnt);
    k_router<<<T_TOK / 4, 256, 0, stream>>>(x, rw, tk_e, tk_p, cnt);
    k_scatter<<<1, 256, 0, stream>>>(cnt, offs, nTiles, tileE, tileRow,
                                     tk_e, tk_p, token_ids, pw);
    // packs: w1 units 8*24*24*2=9216, w2 units 8*6*96*2=9216, x units 40*24*2=1920
    k_packw<<<2304, 256, 0, stream>>>(w1, w1pk, FFN, HID);
    k_packw<<<2304, 256, 0, stream>>>(w2, w2pk, HID, FFN);
    k_packx<<<480, 256, 0, stream>>>(x, token_ids, tileE, tileRow, offs, nTiles, xpk);
    // 1-D grids of 960 (divisible by 8) with XCD-chunked swizzle inside
    k_gemm1_mfma<<<960, 256, 0, stream>>>(
        xpk, w1pk, b1, hmA, tileE, tileRow, offs, nTiles);
    k_gemm2_mfma<<<960, 256, 0, stream>>>(
        hmA, w2pk, b2, out, token_ids, pw, tileE, tileRow, offs, nTiles);
}

// Round 9
// 419.256 us; speedup vs baseline: 1.4915x; 1.4915x over previous
//
#include <hip/hip_runtime.h>
#include <hip/hip_bf16.h>
#include <math.h>

// Problem constants: B=2,S=1024 -> T=2048; E=8,K=2,H=768,F=3072 (fp32 in/out)
#define T_TOK 2048
#define EXP   8
#define HID   768
#define FFN   3072
#define MAXTILES 40     // 128-row tiles: sum_e ceil(cnt_e/128) <= 39

typedef _Float16 f16x8 __attribute__((ext_vector_type(8)));
typedef float    f32x4 __attribute__((ext_vector_type(4)));

// ---------------- workspace layout (bytes) ----------------
// Pack format ("staging-linear", fp16 single plane): per (tile,ktile) an
// 8 KB block of 8 slabs x 1KB; slab = kg*2 + half; within slab [row64][8 f16].
// A staging instruction reads slab_base + lane*16 -> fully contiguous 1 KB.
#define WS_CNT      0
#define WS_OFFS     64
#define WS_NTILES   128
#define WS_TILEE    256
#define WS_TILEROW  1280
#define WS_TKE      4096
#define WS_TKP      20480
#define WS_TOKIDS   36864
#define WS_PW       53248
#define WS_XPK      131072                       // 40*24*8KB   = 7,864,320
#define WS_W1PK     (WS_XPK  + 7864320)          // 8*24*24*8KB = 37,748,736
#define WS_W2PK     (WS_W1PK + 37748736)         // 8*6*96*8KB  = 37,748,736
#define WS_HMA      (WS_W2PK + 37748736)         // 40*96*8KB   = 31,457,280
// end = 114,950,144 (~110 MiB)

// ---------------- helpers ----------------
__device__ __forceinline__ void gload16(const void* g, void* l) {
    __builtin_amdgcn_global_load_lds((__attribute__((address_space(1))) void*)g,
                                     (__attribute__((address_space(3))) void*)l,
                                     16, 0, 0);
}

__device__ __forceinline__ float gelu_exact(float v) {
    return 0.5f * v * (1.0f + erff(v * 0.70710678118654752f));
}

// ---------------- init ----------------
__global__ void k_init(float* __restrict__ out, int* __restrict__ cnt) {
    int idx = blockIdx.x * blockDim.x + threadIdx.x;
    const int n = T_TOK * HID;
    for (int i = idx; i < n; i += gridDim.x * blockDim.x) out[i] = 0.f;
    if (idx < EXP) cnt[idx] = 0;
}

// ---------------- router: one wave per token ----------------
__global__ __launch_bounds__(256) void k_router(
    const float* __restrict__ x, const float* __restrict__ rw,
    int* __restrict__ tk_e, float* __restrict__ tk_p, int* __restrict__ cnt)
{
    int wave = threadIdx.x >> 6;
    int lane = threadIdx.x & 63;
    int t = blockIdx.x * 4 + wave;
    if (t >= T_TOK) return;

    float acc[EXP];
#pragma unroll
    for (int e = 0; e < EXP; ++e) acc[e] = 0.f;
    const float* xr = x + (size_t)t * HID;
#pragma unroll
    for (int i = 0; i < HID / 64; ++i) {
        int k = i * 64 + lane;
        float xv = xr[k];
#pragma unroll
        for (int e = 0; e < EXP; ++e) acc[e] += xv * rw[e * HID + k];
    }
#pragma unroll
    for (int e = 0; e < EXP; ++e) {
        float v = acc[e];
#pragma unroll
        for (int off = 32; off > 0; off >>= 1) v += __shfl_xor(v, off);
        acc[e] = v;
    }
    int e0 = 0; float v0 = acc[0];
#pragma unroll
    for (int e = 1; e < EXP; ++e) if (acc[e] > v0) { v0 = acc[e]; e0 = e; }
    int e1 = -1; float v1 = -INFINITY;
#pragma unroll
    for (int e = 0; e < EXP; ++e) if (e != e0 && acc[e] > v1) { v1 = acc[e]; e1 = e; }
    float ex = expf(v1 - v0);
    float p0 = 1.f / (1.f + ex);
    float p1 = ex / (1.f + ex);

    if (lane == 0) {
        tk_e[t * 2 + 0] = e0; tk_e[t * 2 + 1] = e1;
        tk_p[t * 2 + 0] = p0; tk_p[t * 2 + 1] = p1;
        atomicAdd(&cnt[e0], 1);
        atomicAdd(&cnt[e1], 1);
    }
}

// ---------------- scatter (128-row tiles) ----------------
__global__ __launch_bounds__(256) void k_scatter(
    const int* __restrict__ cnt, int* __restrict__ offs, int* __restrict__ nTiles,
    int* __restrict__ tileE, int* __restrict__ tileRow,
    const int* __restrict__ tk_e, const float* __restrict__ tk_p,
    int* __restrict__ token_ids, float* __restrict__ pw)
{
    __shared__ int fill[EXP];
    __shared__ int offsS[EXP + 1];
    if (threadIdx.x == 0) {
        int o = 0;
        for (int e = 0; e < EXP; ++e) { offsS[e] = o; offs[e] = o; o += cnt[e]; }
        offsS[EXP] = o; offs[EXP] = o;
        int nt = 0;
        for (int e = 0; e < EXP; ++e)
            for (int r = 0; r < cnt[e]; r += 128) {
                tileE[nt] = e; tileRow[nt] = offsS[e] + r; ++nt;
            }
        *nTiles = nt;
    }
    if (threadIdx.x < EXP) fill[threadIdx.x] = 0;
    __syncthreads();
    for (int t = threadIdx.x; t < T_TOK; t += 256) {
#pragma unroll
        for (int kk = 0; kk < 2; ++kk) {
            int e = tk_e[t * 2 + kk];
            int slot = atomicAdd(&fill[e], 1);
            int g = offsS[e] + slot;
            token_ids[g] = t;
            pw[g] = tk_p[t * 2 + kk];
        }
    }
}

// ---------------- weight pack: fp32 [E][N][K] -> staging-linear fp16 ----
// unit = ((e*NTN + nt)*NTK + kt)*2 + half ; one wave per unit.
__global__ __launch_bounds__(256) void k_packw(
    const float* __restrict__ W, short* __restrict__ pk, int N, int K)
{
    int unit = blockIdx.x * 4 + (threadIdx.x >> 6);
    int lane = threadIdx.x & 63;
    int NTN = N >> 7, NTK = K >> 5;
    int half = unit & 1;
    int u2   = unit >> 1;
    int kt   = u2 % NTK;
    int ent  = u2 / NTK;                 // e*NTN + nt
    int nt   = ent % NTN;
    int e    = ent / NTN;
    int row  = nt * 128 + half * 64 + lane;

    const float* src = W + ((size_t)e * N + row) * K + kt * 32;
    f16x8 h4[4];
#pragma unroll
    for (int c = 0; c < 32; c += 4) {
        float4 f = *(const float4*)(src + c);
        h4[c >> 3][(c & 7) + 0] = (_Float16)f.x;
        h4[c >> 3][(c & 7) + 1] = (_Float16)f.y;
        h4[c >> 3][(c & 7) + 2] = (_Float16)f.z;
        h4[c >> 3][(c & 7) + 3] = (_Float16)f.w;
    }
    short* base = pk + ((size_t)ent * NTK + kt) * 4096;
#pragma unroll
    for (int kg = 0; kg < 4; ++kg)
        *(f16x8*)(base + (kg * 2 + half) * 512 + lane * 8) = h4[kg];
}

// ---------------- x pack: gathered token rows -> staging-linear fp16 ----
__global__ __launch_bounds__(256) void k_packx(
    const float* __restrict__ x, const int* __restrict__ token_ids,
    const int* __restrict__ tileE, const int* __restrict__ tileRow,
    const int* __restrict__ offs, const int* __restrict__ nTiles,
    short* __restrict__ xpk)
{
    int unit = blockIdx.x * 4 + (threadIdx.x >> 6);
    int lane = threadIdx.x & 63;
    int half = unit & 1;
    int u2   = unit >> 1;
    int kt   = u2 % 24;
    int tile = u2 / 24;
    if (tile >= *nTiles) return;
    int e = tileE[tile];
    int rowEnd = offs[e + 1];
    int g = min(tileRow[tile] + half * 64 + lane, rowEnd - 1);
    int t = token_ids[g];

    const float* src = x + (size_t)t * HID + kt * 32;
    f16x8 h4[4];
#pragma unroll
    for (int c = 0; c < 32; c += 4) {
        float4 f = *(const float4*)(src + c);
        h4[c >> 3][(c & 7) + 0] = (_Float16)f.x;
        h4[c >> 3][(c & 7) + 1] = (_Float16)f.y;
        h4[c >> 3][(c & 7) + 2] = (_Float16)f.z;
        h4[c >> 3][(c & 7) + 3] = (_Float16)f.w;
    }
    short* base = xpk + ((size_t)tile * 24 + kt) * 4096;
#pragma unroll
    for (int kg = 0; kg < 4; ++kg)
        *(f16x8*)(base + (kg * 2 + half) * 512 + lane * 8) = h4[kg];
}

// ================= MFMA GEMMs: fp16 single-plane, 128x128 tile ============
// TK=32. 4 waves 2x2, wave tile 64x64 = 4x4 frags, 16 MFMA/wave/iter.
// R7-style pipeline (measured best): double-buffered LDS, prefetch issued
// BEFORE compute, one __syncthreads per K-step. 32 KB total LDS ->
// 5 blocks/CU (R8 lesson: occupancy beats deep per-block pipelining here).
// All staging loads contiguous 1KB; LDS frag reads 16B/lane (conflict-free).
// LDS per buffer: [ab(2)][kg(4)][row(128)][8 f16] = 16 KB.

#define DBUF 8192    // shorts per buffer (16 KB); 2 buffers

__global__ __launch_bounds__(256) void k_gemm1_mfma(
    const short* __restrict__ xpk, const short* __restrict__ w1pk,
    const float* __restrict__ b1, short* __restrict__ hmA,
    const int* __restrict__ tileE, const int* __restrict__ tileRow,
    const int* __restrict__ offs, const int* __restrict__ nTiles)
{
    const int lin = blockIdx.x;                 // 0..959
    const int swz = (lin & 7) * 120 + (lin >> 3);
    const int bx   = swz % 24;                  // N-block (24 x 128 = 3072)
    const int tile = swz / 24;
    if (tile >= *nTiles) return;
    const int e = tileE[tile];
    const int rowBase = tileRow[tile];
    const int rowEnd = offs[e + 1];
    const int n0 = bx * 128;

    __shared__ __align__(16) short S[2][DBUF];   // 32 KB

    const int tid = threadIdx.x;
    const int lane = tid & 63;
    const int w = tid >> 6;
    const int wm = w & 1, wn = w >> 1;
    const int l15 = lane & 15, l4 = lane >> 4;

    // 16 slabs (1KB) per K-step, 4 per wave; s = w + j*4:
    // ab=s>>3, kg=(s>>1)&3, h=s&1. jdst = (ab*4+kg)*1024 + h*512 shorts.
    const short* jsrc[4];
    int jdst[4];
#pragma unroll
    for (int j = 0; j < 4; ++j) {
        int s = w + j * 4;
        int ab = s >> 3, kg = (s >> 1) & 3, h = s & 1;
        jdst[j] = (ab * 4 + kg) * 1024 + h * 512;
        if (ab == 0)
            jsrc[j] = xpk + (size_t)tile * 24 * 4096 + s * 512 + lane * 8;
        else
            jsrc[j] = w1pk + ((size_t)(e * 24 + bx) * 24) * 4096
                      + (s - 8) * 512 + lane * 8;
    }

    f32x4 acc[4][4] = {};

#pragma unroll
    for (int j = 0; j < 4; ++j) gload16(jsrc[j], (void*)&S[0][jdst[j]]);
    __syncthreads();

    const int NT = 24;
    for (int kt = 0; kt < NT; ++kt) {
        int cur = kt & 1;
        if (kt + 1 < NT) {                      // issue next-tile loads FIRST
            size_t k0 = (size_t)(kt + 1) * 4096;
#pragma unroll
            for (int j = 0; j < 4; ++j) gload16(jsrc[j] + k0, (void*)&S[cur ^ 1][jdst[j]]);
        }
        const short* base = S[cur];
        f16x8 ah[4], bh[4];
#pragma unroll
        for (int mf = 0; mf < 4; ++mf) {
            int r = wm * 64 + mf * 16 + l15;
            ah[mf] = *(const f16x8*)(base + l4 * 1024 + r * 8);
        }
#pragma unroll
        for (int nf = 0; nf < 4; ++nf) {
            int c = wn * 64 + nf * 16 + l15;
            bh[nf] = *(const f16x8*)(base + (4 + l4) * 1024 + c * 8);
        }
#pragma unroll
        for (int mf = 0; mf < 4; ++mf)
#pragma unroll
            for (int nf = 0; nf < 4; ++nf)
                acc[mf][nf] = __builtin_amdgcn_mfma_f32_16x16x32_f16(ah[mf], bh[nf], acc[mf][nf], 0, 0, 0);
        __syncthreads();
    }

    // epilogue: bias + exact GELU + fp16 store DIRECTLY in gemm2's A-pack
    // C/D map: col = lane&15, row = (lane>>4)*4 + reg   (m89/m91)
#pragma unroll
    for (int mf = 0; mf < 4; ++mf)
#pragma unroll
        for (int nf = 0; nf < 4; ++nf) {
            int f = n0 + wn * 64 + nf * 16 + l15;
            float bias = b1[e * FFN + f];
            int ktf = f >> 5, kg = (f >> 3) & 3, sh = f & 7;
            size_t kbase = ((size_t)tile * 96 + ktf) * 4096 + (kg * 2) * 512 + sh;
#pragma unroll
            for (int j = 0; j < 4; ++j) {
                int row = wm * 64 + mf * 16 + l4 * 4 + j;
                if (rowBase + row < rowEnd) {
                    float v = gelu_exact(acc[mf][nf][j] + bias);
                    size_t o = kbase + (row >> 6) * 512 + (row & 63) * 8;
                    ((_Float16*)hmA)[o] = (_Float16)v;
                }
            }
        }
}

__global__ __launch_bounds__(256) void k_gemm2_mfma(
    const short* __restrict__ hmA, const short* __restrict__ w2pk,
    const float* __restrict__ b2, float* __restrict__ out,
    const int* __restrict__ token_ids, const float* __restrict__ pw,
    const int* __restrict__ tileE, const int* __restrict__ tileRow,
    const int* __restrict__ offs, const int* __restrict__ nTiles)
{
    const int lin = blockIdx.x;                 // 0..959
    const int swz = (lin & 7) * 120 + (lin >> 3);
    const int sub = swz % 24;                   // (x,z) innermost per tile
    const int bx  = sub % 6;                    // N-block (6 x 128 = 768)
    const int z   = sub / 6;                    // split-K = 4
    const int tile = swz / 24;
    if (tile >= *nTiles) return;
    const int e = tileE[tile];
    const int rowBase = tileRow[tile];
    const int rowEnd = offs[e + 1];
    const int n0 = bx * 128;

    __shared__ __align__(16) short S[2][DBUF];   // 32 KB

    const int tid = threadIdx.x;
    const int lane = tid & 63;
    const int w = tid >> 6;
    const int wm = w & 1, wn = w >> 1;
    const int l15 = lane & 15, l4 = lane >> 4;

    const short* jsrc[4];
    int jdst[4];
#pragma unroll
    for (int j = 0; j < 4; ++j) {
        int s = w + j * 4;
        int ab = s >> 3, kg = (s >> 1) & 3, h = s & 1;
        jdst[j] = (ab * 4 + kg) * 1024 + h * 512;
        if (ab == 0)
            jsrc[j] = hmA + ((size_t)tile * 96 + z * 24) * 4096 + s * 512 + lane * 8;
        else
            jsrc[j] = w2pk + ((size_t)(e * 6 + bx) * 96 + z * 24) * 4096
                      + (s - 8) * 512 + lane * 8;
    }

    f32x4 acc[4][4] = {};

#pragma unroll
    for (int j = 0; j < 4; ++j) gload16(jsrc[j], (void*)&S[0][jdst[j]]);
    __syncthreads();

    const int NT = 24;
    for (int kt = 0; kt < NT; ++kt) {
        int cur = kt & 1;
        if (kt + 1 < NT) {
            size_t k0 = (size_t)(kt + 1) * 4096;
#pragma unroll
            for (int j = 0; j < 4; ++j) gload16(jsrc[j] + k0, (void*)&S[cur ^ 1][jdst[j]]);
        }
        const short* base = S[cur];
        f16x8 ah[4], bh[4];
#pragma unroll
        for (int mf = 0; mf < 4; ++mf) {
            int r = wm * 64 + mf * 16 + l15;
            ah[mf] = *(const f16x8*)(base + l4 * 1024 + r * 8);
        }
#pragma unroll
        for (int nf = 0; nf < 4; ++nf) {
            int c = wn * 64 + nf * 16 + l15;
            bh[nf] = *(const f16x8*)(base + (4 + l4) * 1024 + c * 8);
        }
#pragma unroll
        for (int mf = 0; mf < 4; ++mf)
#pragma unroll
            for (int nf = 0; nf < 4; ++nf)
                acc[mf][nf] = __builtin_amdgcn_mfma_f32_16x16x32_f16(ah[mf], bh[nf], acc[mf][nf], 0, 0, 0);
        __syncthreads();
    }

    // epilogue: (acc [+ b2 if z==0]) * p, atomicAdd into out
#pragma unroll
    for (int mf = 0; mf < 4; ++mf)
#pragma unroll
        for (int nf = 0; nf < 4; ++nf) {
            int h = n0 + wn * 64 + nf * 16 + l15;
            float bias = (z == 0) ? b2[e * HID + h] : 0.f;
#pragma unroll
            for (int j = 0; j < 4; ++j) {
                int g = rowBase + wm * 64 + mf * 16 + l4 * 4 + j;
                if (g < rowEnd) {
                    int t = token_ids[g];
                    float p = pw[g];
                    atomicAdd(&out[(size_t)t * HID + h], (acc[mf][nf][j] + bias) * p);
                }
            }
        }
}

// ---------------- launch ----------------
extern "C" void kernel_launch(void* const* d_in, const int* in_sizes, int n_in,
                              void* d_out, int out_size, void* d_ws, size_t ws_size,
                              hipStream_t stream) {
    const float* x  = (const float*)d_in[0];
    const float* rw = (const float*)d_in[1];
    const float* w1 = (const float*)d_in[2];
    const float* b1 = (const float*)d_in[3];
    const float* w2 = (const float*)d_in[4];
    const float* b2 = (const float*)d_in[5];
    float* out = (float*)d_out;

    char* ws = (char*)d_ws;
    int*   cnt       = (int*)(ws + WS_CNT);
    int*   offs      = (int*)(ws + WS_OFFS);
    int*   nTiles    = (int*)(ws + WS_NTILES);
    int*   tileE     = (int*)(ws + WS_TILEE);
    int*   tileRow   = (int*)(ws + WS_TILEROW);
    int*   tk_e      = (int*)(ws + WS_TKE);
    float* tk_p      = (float*)(ws + WS_TKP);
    int*   token_ids = (int*)(ws + WS_TOKIDS);
    float* pw        = (float*)(ws + WS_PW);
    short* xpk  = (short*)(ws + WS_XPK);
    short* w1pk = (short*)(ws + WS_W1PK);
    short* w2pk = (short*)(ws + WS_W2PK);
    short* hmA  = (short*)(ws + WS_HMA);

    k_init<<<1024, 256, 0, stream>>>(out, cnt);
    k_router<<<T_TOK / 4, 256, 0, stream>>>(x, rw, tk_e, tk_p, cnt);
    k_scatter<<<1, 256, 0, stream>>>(cnt, offs, nTiles, tileE, tileRow,
                                     tk_e, tk_p, token_ids, pw);
    // packs: w1 units 8*24*24*2=9216, w2 units 8*6*96*2=9216, x units 40*24*2=1920
    k_packw<<<2304, 256, 0, stream>>>(w1, w1pk, FFN, HID);
    k_packw<<<2304, 256, 0, stream>>>(w2, w2pk, HID, FFN);
    k_packx<<<480, 256, 0, stream>>>(x, token_ids, tileE, tileRow, offs, nTiles, xpk);
    // 1-D grids of 960 (divisible by 8) with XCD-chunked swizzle inside
    k_gemm1_mfma<<<960, 256, 0, stream>>>(
        xpk, w1pk, b1, hmA, tileE, tileRow, offs, nTiles);
    k_gemm2_mfma<<<960, 256, 0, stream>>>(
        hmA, w2pk, b2, out, token_ids, pw, tileE, tileRow, offs, nTiles);
}